// Round 2
// baseline (964.753 us; speedup 1.0000x reference)
//
#include <hip/hip_runtime.h>
#include <math.h>

typedef unsigned short u16;
typedef __bf16  bf16x8 __attribute__((ext_vector_type(8)));
typedef float   f32x4  __attribute__((ext_vector_type(4)));

#define SEQ 1024
#define MR  4096          // BATCH*SEQ rows
#define DIP 2192          // in_proj output width
#define DI  1024          // d_inner
#define NH  16
#define CD  1152          // conv dim

__device__ __forceinline__ u16 f2bf(float f) {
  union { float f; unsigned u; } v; v.f = f;
  unsigned r = v.u + 0x7FFFu + ((v.u >> 16) & 1u);
  return (u16)(r >> 16);
}
__device__ __forceinline__ float bf2f(u16 h) {
  union { unsigned u; float f; } v; v.u = ((unsigned)h) << 16; return v.f;
}
__device__ __forceinline__ void splitbf(float v, u16& h, u16& l) {
  h = f2bf(v); l = f2bf(v - bf2f(h));
}
__device__ __forceinline__ float sigm(float x){ return 1.f/(1.f+__expf(-x)); }

// ---------------- K1: rmsnorm(x) -> fp32 h ----------------
__global__ __launch_bounds__(256) void rmsnorm_x(const float* __restrict__ x,
                                                 const float* __restrict__ w,
                                                 float* __restrict__ hb){
  int m = blockIdx.x, tid = threadIdx.x;
  const float* xr = x + (size_t)m*512;
  float v0 = xr[tid], v1 = xr[tid+256];
  float ss = v0*v0 + v1*v1;
  #pragma unroll
  for (int off=32; off; off>>=1) ss += __shfl_xor(ss, off, 64);
  __shared__ float red[4];
  if ((tid&63)==0) red[tid>>6] = ss;
  __syncthreads();
  float total = red[0]+red[1]+red[2]+red[3];
  float rs = rsqrtf(total*(1.f/512.f) + 1e-5f);
  hb[(size_t)m*512 + tid]     = v0*rs*w[tid];
  hb[(size_t)m*512 + tid+256] = v1*rs*w[tid+256];
}

// ------- split-bf16 MFMA GEMM, C = A @ W^T, fp32 in, fp32 out -------
// A,W fp32 row-major; both split on the fly to (hi,lo) bf16; acc = ah*bh+al*bh+ah*bl.
// MODE 0: in_proj  A=hb (row-flip dir1), W=f/b_in_w,  out fp32 Z[dir], N=2192 K=512
// MODE 1: out_proj A=yg[dir],            W=f/b_out_w, out fp32 ycat (row-unflip dir1, col+dir*512), N=512 K=1024
// MODE 2: final    A=ycat,               W=proj_w,    out fp32 d_out = acc + x, N=512 K=1024
template<int MODE>
__global__ __launch_bounds__(256) void gemm_bt(
    const float* __restrict__ A0, const float* __restrict__ Wf,
    const float* __restrict__ Wb, float* __restrict__ C0,
    const float* __restrict__ X0)
{
  constexpr int K = (MODE==0) ? 512 : 1024;
  constexpr int N = (MODE==0) ? DIP : 512;
  __shared__ __align__(16) u16 sAh[128*32];
  __shared__ __align__(16) u16 sAl[128*32];
  __shared__ __align__(16) u16 sBh[128*32];
  __shared__ __align__(16) u16 sBl[128*32];
  const int tid = threadIdx.x;
  const int dir = blockIdx.z;
  const int m0 = blockIdx.x * 128;
  const int n0 = blockIdx.y * 128;
  const float* A = A0 + ((MODE==1) ? (size_t)dir*MR*K : 0);
  const float* W = dir ? Wb : Wf;
  const int lane = tid & 63;
  const int wid  = tid >> 6;
  const int wm = (wid & 1) * 64;
  const int wn = (wid >> 1) * 64;
  const int quad = lane >> 4;
  const int l16  = lane & 15;
  f32x4 acc[4][4] = {};
  for (int kt = 0; kt < K; kt += 32) {
    __syncthreads();
    #pragma unroll
    for (int it = 0; it < 4; ++it) {
      int chunk = it*256 + tid;        // 1024 float4 chunks per operand
      int row = chunk >> 3;            // 0..127
      int kc  = (chunk & 7) * 4;       // 0..28
      int arow = m0 + row;
      if (MODE==0 && dir) arow = (arow & ~1023) + (1023 - (arow & 1023));  // seq flip
      float4 va = *(const float4*)&A[(size_t)arow*K + kt + kc];
      ushort4 ha, la;
      splitbf(va.x, ha.x, la.x); splitbf(va.y, ha.y, la.y);
      splitbf(va.z, ha.z, la.z); splitbf(va.w, ha.w, la.w);
      *(ushort4*)&sAh[row*32 + kc] = ha;
      *(ushort4*)&sAl[row*32 + kc] = la;
      int wrow = n0 + row;
      if (MODE==0 && wrow >= N) wrow = N-1;   // clamp; garbage cols never stored
      float4 vw = *(const float4*)&W[(size_t)wrow*K + kt + kc];
      ushort4 hw, lw;
      splitbf(vw.x, hw.x, lw.x); splitbf(vw.y, hw.y, lw.y);
      splitbf(vw.z, hw.z, lw.z); splitbf(vw.w, hw.w, lw.w);
      *(ushort4*)&sBh[row*32 + kc] = hw;
      *(ushort4*)&sBl[row*32 + kc] = lw;
    }
    __syncthreads();
    bf16x8 ah[4], al[4], bh[4], bl[4];
    #pragma unroll
    for (int i=0;i<4;i++) {
      ah[i] = *(const bf16x8*)&sAh[(wm + i*16 + l16)*32 + quad*8];
      al[i] = *(const bf16x8*)&sAl[(wm + i*16 + l16)*32 + quad*8];
    }
    #pragma unroll
    for (int j=0;j<4;j++) {
      bh[j] = *(const bf16x8*)&sBh[(wn + j*16 + l16)*32 + quad*8];
      bl[j] = *(const bf16x8*)&sBl[(wn + j*16 + l16)*32 + quad*8];
    }
    #pragma unroll
    for (int i=0;i<4;i++)
      #pragma unroll
      for (int j=0;j<4;j++) {
        f32x4 t = __builtin_amdgcn_mfma_f32_16x16x32_bf16(ah[i], bl[j], acc[i][j], 0,0,0);
        t       = __builtin_amdgcn_mfma_f32_16x16x32_bf16(al[i], bh[j], t,         0,0,0);
        acc[i][j] = __builtin_amdgcn_mfma_f32_16x16x32_bf16(ah[i], bh[j], t,       0,0,0);
      }
  }
  #pragma unroll
  for (int i=0;i<4;i++)
  #pragma unroll
  for (int j=0;j<4;j++)
  #pragma unroll
  for (int r=0;r<4;r++) {
    int mo = m0 + wm + i*16 + quad*4 + r;   // C/D: row=(lane>>4)*4+reg, col=lane&15
    int no = n0 + wn + j*16 + l16;
    float v = acc[i][j][r];
    if (MODE==0) {
      if (no < N) C0[((size_t)dir*MR + mo)*DIP + no] = v;
    } else if (MODE==1) {
      int ro = mo;
      if (dir) ro = (mo & ~1023) + (1023 - (mo & 1023));   // un-flip backward dir
      C0[(size_t)ro*DI + dir*512 + no] = v;
    } else {
      C0[(size_t)mo*512 + no] = v + X0[(size_t)mo*512 + no];
    }
  }
}

// ---------------- K3: depthwise conv + SiLU + dt/softplus/decay ----------------
__global__ __launch_bounds__(256) void conv_dt(
  const float* __restrict__ Z,
  const float* __restrict__ f_cw, const float* __restrict__ f_cb,
  const float* __restrict__ b_cw, const float* __restrict__ b_cb,
  const float* __restrict__ f_dtb, const float* __restrict__ b_dtb,
  const float* __restrict__ f_Al, const float* __restrict__ b_Al,
  float* __restrict__ xconv,
  float* __restrict__ Bc, float* __restrict__ Cc,
  float* __restrict__ dtq, float* __restrict__ decay)
{
  int bm = blockIdx.x;             // dir*4096 + b*1024 + t  (local time)
  int dir = bm >> 12;
  int t = bm & 1023;
  const float* cw  = dir ? b_cw : f_cw;
  const float* cb  = dir ? b_cb : f_cb;
  const float* dtb = dir ? b_dtb : f_dtb;
  const float* Al  = dir ? b_Al : f_Al;
  for (int c = threadIdx.x; c < CD; c += 256) {
    float acc = cb[c];
    #pragma unroll
    for (int k = 0; k < 4; ++k) {
      int tt = t - 3 + k;
      if (tt >= 0) acc = fmaf(Z[((size_t)bm - 3 + k)*DIP + 1024 + c], cw[c*4+k], acc);
    }
    float v = acc * sigm(acc);     // silu
    if (c < DI) {
      xconv[(size_t)bm*DI + c] = v;
    } else if (c < DI + 64) {
      Bc[(size_t)bm*64 + (c - DI)] = v;
    } else {
      Cc[(size_t)bm*64 + (c - DI - 64)] = v;
    }
  }
  if (threadIdx.x < NH) {
    int h = threadIdx.x;
    float dtraw = Z[(size_t)bm*DIP + 2176 + h] + dtb[h];
    float dt = (dtraw > 20.f) ? dtraw : log1pf(__expf(dtraw));
    dtq  [(size_t)bm*NH + h] = dt;
    decay[(size_t)bm*NH + h] = __expf(dt * (-__expf(Al[h])));
  }
}

// ---------------- K4: selective scan. wave=(dir,b,h,p), lane=n ----------------
__global__ __launch_bounds__(256) void scan_kernel(
  const float* __restrict__ decay, const float* __restrict__ dtq,
  const float* __restrict__ xconv,
  const float* __restrict__ Bc, const float* __restrict__ Cc,
  float* __restrict__ yraw)
{
  int wid  = blockIdx.x * 4 + (threadIdx.x >> 6);   // 0..8191
  int lane = threadIdx.x & 63;
  int p = wid & 63;
  int h = (wid >> 6) & 15;
  size_t base = (size_t)(wid & ~1023);              // dir*4096 + b*1024
  const float* dec_p = decay + base*NH + h;
  const float* dt_p  = dtq   + base*NH + h;
  const float* xc_p  = xconv + base*DI + h*64 + p;
  const float* B_p   = Bc    + base*64 + lane;
  const float* C_p   = Cc    + base*64 + lane;
  float*       y_p   = yraw  + base*DI + h*64 + p;
  float hs = 0.f;
  for (int t = 0; t < SEQ; ++t) {
    float dec = dec_p[t*NH];            // wave-uniform
    float dx  = dt_p[t*NH] * xc_p[(size_t)t*DI];  // wave-uniform
    float Bv  = B_p[t*64];              // coalesced over lanes
    float Cv  = C_p[t*64];
    hs = fmaf(hs, dec, dx*Bv);
    float pr = hs * Cv;
    #pragma unroll
    for (int off=32; off; off>>=1) pr += __shfl_xor(pr, off, 64);
    if (lane == 0) y_p[(size_t)t*DI] = pr;
  }
}

// ---------------- K5: +x*D, gate silu(z), rmsnorm -> fp32 yg ----------------
__global__ __launch_bounds__(256) void gate_norm(
  const float* __restrict__ yraw, const float* __restrict__ xconv,
  const float* __restrict__ Z,
  const float* __restrict__ f_D, const float* __restrict__ b_D,
  const float* __restrict__ f_gw, const float* __restrict__ b_gw,
  float* __restrict__ yg)
{
  int bm = blockIdx.x, tid = threadIdx.x;
  int dir = bm >> 12;
  const float* Dp = dir ? b_D : f_D;
  const float* gw = dir ? b_gw : f_gw;
  const float* yr = yraw  + (size_t)bm*DI;
  const float* xc = xconv + (size_t)bm*DI;
  const float* zr = Z     + (size_t)bm*DIP;   // z = cols 0..1023
  float vloc[4]; float ss = 0.f;
  #pragma unroll
  for (int i=0;i<4;i++){
    int c = tid + i*256;
    float yv = yr[c] + xc[c]*Dp[c>>6];
    float z = zr[c];
    float v = yv * (z * sigm(z));
    vloc[i] = v; ss += v*v;
  }
  #pragma unroll
  for (int off=32; off; off>>=1) ss += __shfl_xor(ss, off, 64);
  __shared__ float red[4];
  if ((tid&63)==0) red[tid>>6] = ss;
  __syncthreads();
  float total = red[0]+red[1]+red[2]+red[3];
  float rs = rsqrtf(total*(1.f/1024.f) + 1e-5f);
  #pragma unroll
  for (int i=0;i<4;i++){
    int c = tid + i*256;
    yg[(size_t)bm*DI + c] = vloc[i]*rs*gw[c];
  }
}

extern "C" void kernel_launch(void* const* d_in, const int* in_sizes, int n_in,
                              void* d_out, int out_size, void* d_ws, size_t ws_size,
                              hipStream_t stream)
{
  const float* x        = (const float*)d_in[0];
  const float* norm_w   = (const float*)d_in[1];
  const float* f_in_w   = (const float*)d_in[2];
  const float* f_conv_w = (const float*)d_in[3];
  const float* f_conv_b = (const float*)d_in[4];
  const float* f_dt_bias= (const float*)d_in[5];
  const float* f_A_log  = (const float*)d_in[6];
  const float* f_D      = (const float*)d_in[7];
  const float* f_gw     = (const float*)d_in[8];
  const float* f_out_w  = (const float*)d_in[9];
  const float* b_in_w   = (const float*)d_in[10];
  const float* b_conv_w = (const float*)d_in[11];
  const float* b_conv_b = (const float*)d_in[12];
  const float* b_dt_bias= (const float*)d_in[13];
  const float* b_A_log  = (const float*)d_in[14];
  const float* b_D      = (const float*)d_in[15];
  const float* b_gw     = (const float*)d_in[16];
  const float* b_out_w  = (const float*)d_in[17];
  const float* proj_w   = (const float*)d_in[18];

  char* ws = (char*)d_ws;
  size_t off = 0;
  auto alloc = [&](size_t bytes)->char* {
    char* p = ws + off; off = (off + bytes + 255) & ~(size_t)255; return p;
  };
  float* hb    = (float*)alloc((size_t)MR*512*4);       //  8.4 MB
  float* Z     = (float*)alloc(2*(size_t)MR*DIP*4);     // 71.8 MB
  float* xconv = (float*)alloc(2*(size_t)MR*DI*4);      // 33.5 MB
  float* Bc    = (float*)alloc(2*(size_t)MR*64*4);      //  2.1 MB
  float* Cc    = (float*)alloc(2*(size_t)MR*64*4);      //  2.1 MB
  float* dtq   = (float*)alloc(2*(size_t)MR*NH*4);      //  0.5 MB
  float* decay = (float*)alloc(2*(size_t)MR*NH*4);      //  0.5 MB
  float* yraw  = (float*)alloc(2*(size_t)MR*DI*4);      // 33.5 MB
  float* yg    = (float*)alloc(2*(size_t)MR*DI*4);      // 33.5 MB
  float* ycat  = (float*)alloc((size_t)MR*DI*4);        // 16.8 MB
  // total ~203 MB

  rmsnorm_x<<<MR,256,0,stream>>>(x, norm_w, hb);
  gemm_bt<0><<<dim3(32,18,2),256,0,stream>>>(hb, f_in_w, b_in_w, Z, nullptr);
  conv_dt<<<2*MR,256,0,stream>>>(Z, f_conv_w, f_conv_b, b_conv_w, b_conv_b,
                                 f_dt_bias, b_dt_bias, f_A_log, b_A_log,
                                 xconv, Bc, Cc, dtq, decay);
  scan_kernel<<<2048,256,0,stream>>>(decay, dtq, xconv, Bc, Cc, yraw);
  gate_norm<<<2*MR,256,0,stream>>>(yraw, xconv, Z, f_D, b_D, f_gw, b_gw, yg);
  gemm_bt<1><<<dim3(32,4,2),256,0,stream>>>(yg, f_out_w, b_out_w, ycat, nullptr);
  gemm_bt<2><<<dim3(32,4,1),256,0,stream>>>(ycat, proj_w, proj_w, d_out ? (float*)d_out : nullptr, x);
}

// Round 3
// 630.535 us; speedup vs baseline: 1.5301x; 1.5301x over previous
//
#include <hip/hip_runtime.h>
#include <math.h>

typedef unsigned short u16;
typedef __bf16  bf16x8 __attribute__((ext_vector_type(8)));
typedef float   f32x4  __attribute__((ext_vector_type(4)));

#define SEQ 1024
#define MR  4096          // BATCH*SEQ rows
#define DIP 2192          // in_proj output width
#define DI  1024          // d_inner
#define NH  16
#define CD  1152          // conv dim

__device__ __forceinline__ u16 f2bf(float f) {
  union { float f; unsigned u; } v; v.f = f;
  unsigned r = v.u + 0x7FFFu + ((v.u >> 16) & 1u);
  return (u16)(r >> 16);
}
__device__ __forceinline__ float bf2f(u16 h) {
  union { unsigned u; float f; } v; v.u = ((unsigned)h) << 16; return v.f;
}
__device__ __forceinline__ void splitbf(float v, u16& h, u16& l) {
  h = f2bf(v); l = f2bf(v - bf2f(h));
}
__device__ __forceinline__ float sigm(float x){ return 1.f/(1.f+__expf(-x)); }

// ---------------- K1: rmsnorm(x) -> fp32 h ----------------
__global__ __launch_bounds__(256) void rmsnorm_x(const float* __restrict__ x,
                                                 const float* __restrict__ w,
                                                 float* __restrict__ hb){
  int m = blockIdx.x, tid = threadIdx.x;
  const float* xr = x + (size_t)m*512;
  float v0 = xr[tid], v1 = xr[tid+256];
  float ss = v0*v0 + v1*v1;
  #pragma unroll
  for (int off=32; off; off>>=1) ss += __shfl_xor(ss, off, 64);
  __shared__ float red[4];
  if ((tid&63)==0) red[tid>>6] = ss;
  __syncthreads();
  float total = red[0]+red[1]+red[2]+red[3];
  float rs = rsqrtf(total*(1.f/512.f) + 1e-5f);
  hb[(size_t)m*512 + tid]     = v0*rs*w[tid];
  hb[(size_t)m*512 + tid+256] = v1*rs*w[tid+256];
}

// ------- split-bf16 MFMA GEMM, C = A @ W^T, fp32 in, fp32 out -------
template<int MODE>
__global__ __launch_bounds__(256) void gemm_bt(
    const float* __restrict__ A0, const float* __restrict__ Wf,
    const float* __restrict__ Wb, float* __restrict__ C0,
    const float* __restrict__ X0)
{
  constexpr int K = (MODE==0) ? 512 : 1024;
  constexpr int N = (MODE==0) ? DIP : 512;
  __shared__ __align__(16) u16 sAh[128*32];
  __shared__ __align__(16) u16 sAl[128*32];
  __shared__ __align__(16) u16 sBh[128*32];
  __shared__ __align__(16) u16 sBl[128*32];
  const int tid = threadIdx.x;
  const int dir = blockIdx.z;
  const int m0 = blockIdx.x * 128;
  const int n0 = blockIdx.y * 128;
  const float* A = A0 + ((MODE==1) ? (size_t)dir*MR*K : 0);
  const float* W = dir ? Wb : Wf;
  const int lane = tid & 63;
  const int wid  = tid >> 6;
  const int wm = (wid & 1) * 64;
  const int wn = (wid >> 1) * 64;
  const int quad = lane >> 4;
  const int l16  = lane & 15;
  f32x4 acc[4][4] = {};
  for (int kt = 0; kt < K; kt += 32) {
    __syncthreads();
    #pragma unroll
    for (int it = 0; it < 4; ++it) {
      int chunk = it*256 + tid;        // 1024 float4 chunks per operand
      int row = chunk >> 3;            // 0..127
      int kc  = (chunk & 7) * 4;       // 0..28
      int arow = m0 + row;
      if (MODE==0 && dir) arow = (arow & ~1023) + (1023 - (arow & 1023));  // seq flip
      float4 va = *(const float4*)&A[(size_t)arow*K + kt + kc];
      ushort4 ha, la;
      splitbf(va.x, ha.x, la.x); splitbf(va.y, ha.y, la.y);
      splitbf(va.z, ha.z, la.z); splitbf(va.w, ha.w, la.w);
      *(ushort4*)&sAh[row*32 + kc] = ha;
      *(ushort4*)&sAl[row*32 + kc] = la;
      int wrow = n0 + row;
      if (MODE==0 && wrow >= N) wrow = N-1;   // clamp; garbage cols never stored
      float4 vw = *(const float4*)&W[(size_t)wrow*K + kt + kc];
      ushort4 hw, lw;
      splitbf(vw.x, hw.x, lw.x); splitbf(vw.y, hw.y, lw.y);
      splitbf(vw.z, hw.z, lw.z); splitbf(vw.w, hw.w, lw.w);
      *(ushort4*)&sBh[row*32 + kc] = hw;
      *(ushort4*)&sBl[row*32 + kc] = lw;
    }
    __syncthreads();
    bf16x8 ah[4], al[4], bh[4], bl[4];
    #pragma unroll
    for (int i=0;i<4;i++) {
      ah[i] = *(const bf16x8*)&sAh[(wm + i*16 + l16)*32 + quad*8];
      al[i] = *(const bf16x8*)&sAl[(wm + i*16 + l16)*32 + quad*8];
    }
    #pragma unroll
    for (int j=0;j<4;j++) {
      bh[j] = *(const bf16x8*)&sBh[(wn + j*16 + l16)*32 + quad*8];
      bl[j] = *(const bf16x8*)&sBl[(wn + j*16 + l16)*32 + quad*8];
    }
    #pragma unroll
    for (int i=0;i<4;i++)
      #pragma unroll
      for (int j=0;j<4;j++) {
        f32x4 t = __builtin_amdgcn_mfma_f32_16x16x32_bf16(ah[i], bl[j], acc[i][j], 0,0,0);
        t       = __builtin_amdgcn_mfma_f32_16x16x32_bf16(al[i], bh[j], t,         0,0,0);
        acc[i][j] = __builtin_amdgcn_mfma_f32_16x16x32_bf16(ah[i], bh[j], t,       0,0,0);
      }
  }
  #pragma unroll
  for (int i=0;i<4;i++)
  #pragma unroll
  for (int j=0;j<4;j++)
  #pragma unroll
  for (int r=0;r<4;r++) {
    int mo = m0 + wm + i*16 + quad*4 + r;   // C/D: row=(lane>>4)*4+reg, col=lane&15
    int no = n0 + wn + j*16 + l16;
    float v = acc[i][j][r];
    if (MODE==0) {
      if (no < N) C0[((size_t)dir*MR + mo)*DIP + no] = v;
    } else if (MODE==1) {
      int ro = mo;
      if (dir) ro = (mo & ~1023) + (1023 - (mo & 1023));   // un-flip backward dir
      C0[(size_t)ro*DI + dir*512 + no] = v;
    } else {
      C0[(size_t)mo*512 + no] = v + X0[(size_t)mo*512 + no];
    }
  }
}

// ---------------- K3: depthwise conv + SiLU + dt softplus ----------------
__global__ __launch_bounds__(256) void conv_dt(
  const float* __restrict__ Z,
  const float* __restrict__ f_cw, const float* __restrict__ f_cb,
  const float* __restrict__ b_cw, const float* __restrict__ b_cb,
  const float* __restrict__ f_dtb, const float* __restrict__ b_dtb,
  float* __restrict__ xconv,
  float* __restrict__ Bc, float* __restrict__ Cc,
  float* __restrict__ dtq)
{
  int bm = blockIdx.x;             // dirb*1024 + t
  int dir = bm >> 12;
  int t = bm & 1023;
  const float* cw  = dir ? b_cw : f_cw;
  const float* cb  = dir ? b_cb : f_cb;
  const float* dtb = dir ? b_dtb : f_dtb;
  for (int c = threadIdx.x; c < CD; c += 256) {
    float acc = cb[c];
    #pragma unroll
    for (int k = 0; k < 4; ++k) {
      int tt = t - 3 + k;
      if (tt >= 0) acc = fmaf(Z[((size_t)bm - 3 + k)*DIP + 1024 + c], cw[c*4+k], acc);
    }
    float v = acc * sigm(acc);     // silu
    if (c < DI) {
      xconv[(size_t)bm*DI + c] = v;
    } else if (c < DI + 64) {
      Bc[(size_t)bm*64 + (c - DI)] = v;
    } else {
      Cc[(size_t)bm*64 + (c - DI - 64)] = v;
    }
  }
  if (threadIdx.x < NH) {
    int h = threadIdx.x;
    float dtraw = Z[(size_t)bm*DIP + 2176 + h] + dtb[h];
    float dt = (dtraw > 20.f) ? dtraw : log1pf(__expf(dtraw));
    dtq[(size_t)bm*NH + h] = dt;
  }
}

// ---------- K4a: chunked local scan, lane=p, hs[n] in VGPRs (no cross-lane) ----------
// block = (dirb 8, chunk 16, hq 4) -> 512 blocks; 4 waves = 4 heads sharing B/C LDS stage.
__global__ __launch_bounds__(256,4) void scan_chunk(
  const float* __restrict__ dtq, const float* __restrict__ xconv,
  const float* __restrict__ Bc, const float* __restrict__ Cc,
  const float* __restrict__ f_Al, const float* __restrict__ b_Al,
  float* __restrict__ yraw, float* __restrict__ cumdec, float* __restrict__ S)
{
  __shared__ __align__(16) float sB[4096];
  __shared__ __align__(16) float sC[4096];
  int bx = blockIdx.x;
  int hq = bx & 3, chunk = (bx>>2)&15, dirb = bx>>6;
  int w = threadIdx.x >> 6, lane = threadIdx.x & 63;
  int h = hq*4 + w;
  int base_row = dirb*1024 + chunk*64;
  const float4* Bg = (const float4*)(Bc + (size_t)base_row*64);
  const float4* Cg = (const float4*)(Cc + (size_t)base_row*64);
  for (int i = threadIdx.x; i < 1024; i += 256) {
    ((float4*)sB)[i] = Bg[i];
    ((float4*)sC)[i] = Cg[i];
  }
  __syncthreads();
  const float* Al = (dirb >= 4) ? b_Al : f_Al;
  float A = -__expf(Al[h]);
  float hs[64];
  #pragma unroll
  for (int n=0;n<64;n++) hs[n]=0.f;
  float cd = 1.f;
  const float* dt_p = dtq   + (size_t)base_row*16 + h;
  const float* x_p  = xconv + (size_t)base_row*1024 + h*64 + lane;
  float*       y_p  = yraw  + (size_t)base_row*1024 + h*64 + lane;
  float*       cd_p = cumdec+ (size_t)base_row*16 + h;
  for (int j=0;j<64;j++) {
    float dt = dt_p[j*16];                // wave-uniform
    float x  = x_p[(size_t)j*1024];       // coalesced over lanes
    float dec = __expf(dt*A);
    float dx = dt*x;
    cd *= dec;
    float y = 0.f;
    #pragma unroll
    for (int n4=0;n4<16;n4++) {
      float4 b4 = *(const float4*)&sB[j*64 + n4*4];  // broadcast ds_read_b128
      float4 c4 = *(const float4*)&sC[j*64 + n4*4];
      hs[n4*4+0] = fmaf(hs[n4*4+0], dec, dx*b4.x); y = fmaf(hs[n4*4+0], c4.x, y);
      hs[n4*4+1] = fmaf(hs[n4*4+1], dec, dx*b4.y); y = fmaf(hs[n4*4+1], c4.y, y);
      hs[n4*4+2] = fmaf(hs[n4*4+2], dec, dx*b4.z); y = fmaf(hs[n4*4+2], c4.z, y);
      hs[n4*4+3] = fmaf(hs[n4*4+3], dec, dx*b4.w); y = fmaf(hs[n4*4+3], c4.w, y);
    }
    y_p[(size_t)j*1024] = y;
    if (lane == 0) cd_p[j*16] = cd;
  }
  // store local chunk state, layout S[inst][n][p] (coalesced over lane=p)
  size_t inst = ((size_t)(dirb*16+h)*16 + chunk)*4096;
  #pragma unroll
  for (int n=0;n<64;n++) S[inst + n*64 + lane] = hs[n];
}

// ---------- K4b: inter-chunk combine; S[c] overwritten in-place with h_start(c) ----------
__global__ __launch_bounds__(256) void scan_comb(
  const float* __restrict__ cumdec, float* __restrict__ S)
{
  int sub = blockIdx.x & 3, ih = blockIdx.x >> 2;   // ih = dirb*16+h
  int dirb = ih >> 4, h = ih & 15;
  float hr[4] = {0.f,0.f,0.f,0.f};
  for (int c=0;c<16;c++) {
    float P = cumdec[((size_t)(dirb*1024 + c*64 + 63))*16 + h];  // chunk total decay
    size_t base = ((size_t)ih*16 + c)*4096 + sub*1024 + threadIdx.x;
    #pragma unroll
    for (int k=0;k<4;k++) {
      float s = S[base + k*256];
      S[base + k*256] = hr[k];          // h_start for chunk c
      hr[k] = fmaf(hr[k], P, s);
    }
  }
}

// ---------- K4c: correction y += cumdec * (C_t . h_start), lane=p ----------
__global__ __launch_bounds__(256,4) void scan_fix(
  const float* __restrict__ Cc, const float* __restrict__ cumdec,
  const float* __restrict__ S, float* __restrict__ yraw)
{
  int bx = blockIdx.x;
  int hq = bx & 3, chunk = (bx>>2)&15, dirb = bx>>6;
  if (chunk == 0) return;               // h_start = 0, block-uniform exit
  __shared__ __align__(16) float sC[4096];
  int w = threadIdx.x >> 6, lane = threadIdx.x & 63;
  int h = hq*4 + w;
  int base_row = dirb*1024 + chunk*64;
  const float4* Cg = (const float4*)(Cc + (size_t)base_row*64);
  for (int i = threadIdx.x; i < 1024; i += 256) ((float4*)sC)[i] = Cg[i];
  __syncthreads();
  size_t inst = ((size_t)(dirb*16+h)*16 + chunk)*4096;
  float hv[64];
  #pragma unroll
  for (int n=0;n<64;n++) hv[n] = S[inst + n*64 + lane];   // h_start[p=lane][n]
  const float* cd_p = cumdec + (size_t)base_row*16 + h;
  float* y_p = yraw + (size_t)base_row*1024 + h*64 + lane;
  for (int j=0;j<64;j++) {
    float cdj = cd_p[j*16];
    float y = 0.f;
    #pragma unroll
    for (int n4=0;n4<16;n4++) {
      float4 c4 = *(const float4*)&sC[j*64 + n4*4];
      y = fmaf(hv[n4*4+0], c4.x, y);
      y = fmaf(hv[n4*4+1], c4.y, y);
      y = fmaf(hv[n4*4+2], c4.z, y);
      y = fmaf(hv[n4*4+3], c4.w, y);
    }
    y_p[(size_t)j*1024] += cdj * y;
  }
}

// ---------------- K5: +x*D, gate silu(z), rmsnorm -> in-place yraw ----------------
__global__ __launch_bounds__(256) void gate_norm(
  float* __restrict__ yraw, const float* __restrict__ xconv,
  const float* __restrict__ Z,
  const float* __restrict__ f_D, const float* __restrict__ b_D,
  const float* __restrict__ f_gw, const float* __restrict__ b_gw)
{
  int bm = blockIdx.x, tid = threadIdx.x;
  int dir = bm >> 12;
  const float* Dp = dir ? b_D : f_D;
  const float* gw = dir ? b_gw : f_gw;
  float* yr = yraw  + (size_t)bm*DI;
  const float* xc = xconv + (size_t)bm*DI;
  const float* zr = Z     + (size_t)bm*DIP;   // z = cols 0..1023
  float vloc[4]; float ss = 0.f;
  #pragma unroll
  for (int i=0;i<4;i++){
    int c = tid + i*256;
    float yv = yr[c] + xc[c]*Dp[c>>6];
    float z = zr[c];
    float v = yv * (z * sigm(z));
    vloc[i] = v; ss += v*v;
  }
  #pragma unroll
  for (int off=32; off; off>>=1) ss += __shfl_xor(ss, off, 64);
  __shared__ float red[4];
  if ((tid&63)==0) red[tid>>6] = ss;
  __syncthreads();
  float total = red[0]+red[1]+red[2]+red[3];
  float rs = rsqrtf(total*(1.f/1024.f) + 1e-5f);
  #pragma unroll
  for (int i=0;i<4;i++){
    int c = tid + i*256;
    yr[c] = vloc[i]*rs*gw[c];
  }
}

extern "C" void kernel_launch(void* const* d_in, const int* in_sizes, int n_in,
                              void* d_out, int out_size, void* d_ws, size_t ws_size,
                              hipStream_t stream)
{
  const float* x        = (const float*)d_in[0];
  const float* norm_w   = (const float*)d_in[1];
  const float* f_in_w   = (const float*)d_in[2];
  const float* f_conv_w = (const float*)d_in[3];
  const float* f_conv_b = (const float*)d_in[4];
  const float* f_dt_bias= (const float*)d_in[5];
  const float* f_A_log  = (const float*)d_in[6];
  const float* f_D      = (const float*)d_in[7];
  const float* f_gw     = (const float*)d_in[8];
  const float* f_out_w  = (const float*)d_in[9];
  const float* b_in_w   = (const float*)d_in[10];
  const float* b_conv_w = (const float*)d_in[11];
  const float* b_conv_b = (const float*)d_in[12];
  const float* b_dt_bias= (const float*)d_in[13];
  const float* b_A_log  = (const float*)d_in[14];
  const float* b_D      = (const float*)d_in[15];
  const float* b_gw     = (const float*)d_in[16];
  const float* b_out_w  = (const float*)d_in[17];
  const float* proj_w   = (const float*)d_in[18];

  char* ws = (char*)d_ws;
  size_t off = 0;
  auto alloc = [&](size_t bytes)->char* {
    char* p = ws + off; off = (off + bytes + 255) & ~(size_t)255; return p;
  };
  float* hb     = (float*)alloc((size_t)MR*512*4);       //  8.4 MB
  float* Z      = (float*)alloc(2*(size_t)MR*DIP*4);     // 71.8 MB
  float* xconv  = (float*)alloc(2*(size_t)MR*DI*4);      // 33.5 MB
  float* Bc     = (float*)alloc(2*(size_t)MR*64*4);      //  2.1 MB
  float* Cc     = (float*)alloc(2*(size_t)MR*64*4);      //  2.1 MB
  float* dtq    = (float*)alloc(2*(size_t)MR*NH*4);      //  0.5 MB
  float* cumdec = (float*)alloc(2*(size_t)MR*NH*4);      //  0.5 MB
  float* S      = (float*)alloc((size_t)2048*4096*4);    // 33.5 MB
  float* yraw   = (float*)alloc(2*(size_t)MR*DI*4);      // 33.5 MB
  float* ycat   = (float*)alloc((size_t)MR*DI*4);        // 16.8 MB
  // total ~203 MB

  rmsnorm_x<<<MR,256,0,stream>>>(x, norm_w, hb);
  gemm_bt<0><<<dim3(32,18,2),256,0,stream>>>(hb, f_in_w, b_in_w, Z, nullptr);
  conv_dt<<<2*MR,256,0,stream>>>(Z, f_conv_w, f_conv_b, b_conv_w, b_conv_b,
                                 f_dt_bias, b_dt_bias, xconv, Bc, Cc, dtq);
  scan_chunk<<<512,256,0,stream>>>(dtq, xconv, Bc, Cc, f_A_log, b_A_log,
                                   yraw, cumdec, S);
  scan_comb<<<512,256,0,stream>>>(cumdec, S);
  scan_fix<<<512,256,0,stream>>>(Cc, cumdec, S, yraw);
  gate_norm<<<2*MR,256,0,stream>>>(yraw, xconv, Z, f_D, b_D, f_gw, b_gw);
  gemm_bt<1><<<dim3(32,4,2),256,0,stream>>>(yraw, f_out_w, b_out_w, ycat, nullptr);
  gemm_bt<2><<<dim3(32,4,1),256,0,stream>>>(ycat, proj_w, proj_w, (float*)d_out, x);
}